// Round 10
// baseline (32.069 us; speedup 1.0000x reference)
//
#include <hip/hip_runtime.h>
#include <hip/hip_fp16.h>
#include <math.h>

// x: (32,32,32,32) f32; 6 layers, O=64 trees, gates/layer = 32,16,8,4,2,1
// out: (32,64,32,32) f32
//
// Fused-expansion formulation: the root gate's dependency cone expanded as a
// binary tree = 63 nodes. Precompute expanded coefs -> evaluation has ONLY
// static indices: t1[n] = gate(t0[2n], t0[2n+1]).
//
// Leaf storage: fp16 DUAL slab in LDS. Slab A halfword c = xval(col c-1),
// slab B halfword c = xval(col c) (one-halfword shift). A lane owning cols
// (j, j+1) reads both as ONE dword: even halfword start -> slab A dword h/2,
// odd start -> slab B dword (h-1)/2. Builder resolves slab+dword statically.
// Row stride 48 halfwords = 24 dwords -> 64-lane b32 pattern hits every bank
// exactly 2x (free).
//
// d_ws layout (dwords), per tree o (288 dwords, 16B aligned):
//   tab[o*288 + 0..31]    packed leaf dword offsets (dwa | dwb<<16), L0 node n
//   tab[o*288 + 32..283]  float4 coefs, slots: L0 n->n, L1->32+n, L2->48+n,
//                         L3->56+n, L4->60+n, L5->62

struct Tabs { const int* ia[6]; const int* ib[6]; const float* w[6]; };

__device__ __constant__ float GM[64] = {
  0,0,0,0,   0,0,0,1,   0,1,0,-1,  0,1,0,0,
  0,0,1,-1,  0,0,1,0,   0,1,1,-2,  0,1,1,-1,
  1,-1,-1,1, 1,-1,-1,2, 1,0,-1,0,  1,0,-1,1,
  1,-1,0,0,  1,-1,0,1,  1,0,0,-1,  1,0,0,0 };

typedef float v2f __attribute__((ext_vector_type(2)));

// packed gate: y = c0 + c1*a + c2*b + c3*a*b on both pixels at once
// = fma(c2,b, fma(a, fma(c3,b,c1), c0))  -> 3x v_pk_fma_f32
__device__ __forceinline__ v2f gatep(v2f a, v2f b, float4 c) {
  v2f t = __builtin_elementwise_fma((v2f)c.w, b, (v2f)c.y);
  t = __builtin_elementwise_fma(a, t, (v2f)c.x);
  return __builtin_elementwise_fma((v2f)c.z, b, t);
}

// ---- builder: one thread per expanded node; walks its own root->node path ----
__global__ __launch_bounds__(256) void build_tree(Tabs t, unsigned* __restrict tab) {
  const int gid = blockIdx.x * 256 + threadIdx.x;     // [0, 4096)
  const int o = gid >> 6, slot = gid & 63;
  if (slot >= 63) return;
  int L, m;
  if      (slot < 32) { L = 0; m = slot;      }
  else if (slot < 48) { L = 1; m = slot - 32; }
  else if (slot < 56) { L = 2; m = slot - 48; }
  else if (slot < 60) { L = 3; m = slot - 56; }
  else if (slot < 62) { L = 4; m = slot - 60; }
  else                { L = 5; m = 0;         }
  const int dcnt[6] = {32, 16, 8, 4, 2, 1};
  const int d = 5 - L;                 // path length from root
  int g = 0;                           // gate id at current level (root = gate 0)
  for (int step = 0; step < d; ++step) {
    int lyr = 5 - step;
    int bit = (m >> (d - 1 - step)) & 1;
    g = (bit ? t.ib[lyr] : t.ia[lyr])[o * dcnt[lyr] + g];
  }

  // coefficients: softmax(w[L][o, g]) @ GATE_M
  const float4* wp = (const float4*)(t.w[L] + (o * dcnt[L] + g) * 16);
  float4 w0 = wp[0], w1 = wp[1], w2 = wp[2], w3 = wp[3];
  float wv[16] = { w0.x,w0.y,w0.z,w0.w, w1.x,w1.y,w1.z,w1.w,
                   w2.x,w2.y,w2.z,w2.w, w3.x,w3.y,w3.z,w3.w };
  float mx = -1e30f;
  #pragma unroll
  for (int k = 0; k < 16; ++k) mx = fmaxf(mx, wv[k]);
  float e[16], s = 0.f;
  #pragma unroll
  for (int k = 0; k < 16; ++k) { e[k] = expf(wv[k] - mx); s += e[k]; }
  float inv = 1.0f / s;
  float c0 = 0, c1 = 0, c2 = 0, c3 = 0;
  #pragma unroll
  for (int k = 0; k < 16; ++k) {
    float p = e[k] * inv;
    c0 += p * GM[k*4+0]; c1 += p * GM[k*4+1];
    c2 += p * GM[k*4+2]; c3 += p * GM[k*4+3];
  }
  float4* C = (float4*)(tab + o * 288 + 32);
  float4 c; c.x = c0; c.y = c1; c.z = c2; c.w = c3;
  C[slot] = c;

  if (L == 0) {
    // leaf feature f = ch*9 + ki*3 + kj -> halfword offset in slab geometry
    // [ch][6 rows][48 halfwords]; lane adds rbase*48 + j (even). Parity of
    // builder part selects slab: even -> A dword h/2; odd -> B dword (h-1)/2.
    int ia = t.ia[0][o * 32 + g], ib = t.ib[0][o * 32 + g];
    int ca = ia / 9, ra = ia - ca * 9, kia = ra / 3, kja = ra - kia * 3;
    int cb = ib / 9, rb = ib - cb * 9, kib = rb / 3, kjb = rb - kib * 3;
    int hA = (ca * 6 + kia) * 48 + kja;
    int hB = (cb * 6 + kib) * 48 + kjb;
    unsigned dwa = (hA & 1) ? (unsigned)(((hA - 1) >> 1) + 4608) : (unsigned)(hA >> 1);
    unsigned dwb = (hB & 1) ? (unsigned)(((hB - 1) >> 1) + 4608) : (unsigned)(hB >> 1);
    tab[o * 288 + slot] = dwa | (dwb << 16);
  }
}

// Block: 512 threads = 8 waves sharing one 4-row x 32-col tile.
// Each lane owns 2 adjacent columns; leaf operand = ONE ds_read_b32 (fp16
// pair) + 2 cvt; gate math = 3x v_pk_fma_f32. Each wave evaluates 2 trees
// -> 8192 waves = 32 waves/CU resident (grid 1024 = 4 blocks/CU x 8 waves).
// LDS: dual fp16 slab 2 x 32ch x 6rows x 24 dwords = 36 KiB; x4 = 144 KiB.
// bid bits: [1:0]=treechunk(16 trees), [4:2]=rowchunk(4 rows), [9:5]=batch
__global__ __launch_bounds__(512, 8) void logic_conv(const float* __restrict x,
                                                     const unsigned* __restrict tab,
                                                     float* __restrict out) {
  __shared__ unsigned xr[9216];                  // A: [0,4608), B: [4608,9216)
  const int bid = blockIdx.x;
  const int tc = bid & 3, rc = (bid >> 2) & 7, b = bid >> 5;
  const int r0 = rc * 4;
  const int tid = threadIdx.x;

  // stage dual fp16 slab: A dword k = (xval(2kk-1), xval(2kk)),
  //                       B dword k = (xval(2kk),   xval(2kk+1))
  // rows r0-1 .. r0+4, zero-padded OOB. 3 shared loads -> 2 packed writes.
  for (int k = tid; k < 4608; k += 512) {
    int ch = k / 144, rem = k - ch * 144;
    int rr = rem / 24, kk = rem - rr * 24;
    int gr = r0 - 1 + rr;
    int gc = 2 * kk - 1;
    float fm = 0.f, f0 = 0.f, fp = 0.f;
    if ((unsigned)gr < 32u) {
      const float* base = x + ((b * 32 + ch) * 32 + gr) * 32;
      if ((unsigned)gc < 32u)       fm = base[gc];
      if ((unsigned)(gc + 1) < 32u) f0 = base[gc + 1];
      if ((unsigned)(gc + 2) < 32u) fp = base[gc + 2];
    }
    unsigned hm = __half_as_ushort(__float2half(fm));
    unsigned h0 = __half_as_ushort(__float2half(f0));
    unsigned hp = __half_as_ushort(__float2half(fp));
    xr[k]        = hm | (h0 << 16);
    xr[k + 4608] = h0 | (hp << 16);
  }
  __syncthreads();

  const int w = tid >> 6;              // wave id 0..7 -> tree pair
  const int lane = tid & 63;
  const int rbase = lane >> 4;         // 0..3 relative output row
  const int jh = lane & 15;            // col-pair index; cols j=2*jh, 2*jh+1
  const int ldw = rbase * 24 + jh;     // lane dword offset into a slab row blk
  const int o0 = tc * 16 + w * 2;      // first tree for this wave
  float* outb = out + ((b * 64 + o0) * 32 + (r0 + rbase)) * 32 + 2 * jh;

  for (int t = 0; t < 2; ++t) {
    const int o = __builtin_amdgcn_readfirstlane(o0 + t);   // uniform -> s_load
    const unsigned* __restrict T = tab + o * 288;
    const float4*  __restrict C = (const float4*)(T + 32);

    // fused L0+L1: consume leaf pairs immediately (caps VGPR pressure)
    v2f t1[16];
    #pragma unroll
    for (int n = 0; n < 16; ++n) {
      unsigned ipA = T[2*n], ipB = T[2*n+1];
      unsigned da = xr[(int)(ipA & 0xffffu) + ldw];
      unsigned db = xr[(int)(ipA >> 16) + ldw];
      float2 fa = __half22float2(*reinterpret_cast<__half2*>(&da));
      float2 fb = __half22float2(*reinterpret_cast<__half2*>(&db));
      v2f a = {fa.x, fa.y}, bb = {fb.x, fb.y};
      v2f u = gatep(a, bb, C[2*n]);
      unsigned dc = xr[(int)(ipB & 0xffffu) + ldw];
      unsigned dd = xr[(int)(ipB >> 16) + ldw];
      float2 fc = __half22float2(*reinterpret_cast<__half2*>(&dc));
      float2 fd = __half22float2(*reinterpret_cast<__half2*>(&dd));
      v2f cc = {fc.x, fc.y}, ddv = {fd.x, fd.y};
      v2f v = gatep(cc, ddv, C[2*n+1]);
      t1[n] = gatep(u, v, C[32 + n]);
    }
    v2f t2[8];
    #pragma unroll
    for (int n = 0; n < 8; ++n) t2[n] = gatep(t1[2*n], t1[2*n+1], C[48 + n]);
    v2f t3[4];
    #pragma unroll
    for (int n = 0; n < 4; ++n) t3[n] = gatep(t2[2*n], t2[2*n+1], C[56 + n]);
    v2f t4[2];
    #pragma unroll
    for (int n = 0; n < 2; ++n) t4[n] = gatep(t3[2*n], t3[2*n+1], C[60 + n]);
    {
      v2f r = gatep(t4[0], t4[1], C[62]);
      float2 rr; rr.x = r.x; rr.y = r.y;
      *(float2*)outb = rr;                       // 8B aligned (col even)
    }
    outb += 1024;                      // next tree: +32*32
  }
}

extern "C" void kernel_launch(void* const* d_in, const int* in_sizes, int n_in,
                              void* d_out, int out_size, void* d_ws, size_t ws_size,
                              hipStream_t stream) {
  const float* x = (const float*)d_in[0];
  Tabs tabs;
  for (int l = 0; l < 6; ++l) {
    tabs.ia[l] = (const int*)d_in[1 + 3 * l];
    tabs.ib[l] = (const int*)d_in[2 + 3 * l];
    tabs.w[l]  = (const float*)d_in[3 + 3 * l];
  }
  unsigned* tab = (unsigned*)d_ws;     // 64 trees * 288 dwords = 73.7 KB
  build_tree<<<16, 256, 0, stream>>>(tabs, tab);
  logic_conv<<<1024, 512, 0, stream>>>(x, tab, (float*)d_out);
}